// Round 8
// baseline (888.234 us; speedup 1.0000x reference)
//
#include <hip/hip_runtime.h>

#define NN 100000
#define NE 1600000
#define DIM 64
#define NR 391      // regions = ceil(NN/256), dst>>8
#define IDXCAP 2048 // LDS-staged csr2 slice cap per 64-node block (mean 1024, 32 sigma)

typedef unsigned short u16;
typedef unsigned int u32;

__device__ __forceinline__ u16 f2b(float f) {  // f32 -> bf16 RNE
  union { float f; u32 u; } c; c.f = f;
  u32 u = c.u;
  u += 0x7FFF + ((u >> 16) & 1);
  return (u16)(u >> 16);
}
__device__ __forceinline__ float b2f(u16 h) {
  union { u32 u; float f; } c; c.u = ((u32)h) << 16;
  return c.f;
}
__device__ __forceinline__ float blo(u32 v) {
  union { u32 u; float f; } c; c.u = v << 16;
  return c.f;
}
__device__ __forceinline__ float bhi(u32 v) {
  union { u32 u; float f; } c; c.u = v & 0xFFFF0000u;
  return c.f;
}

// x (f32) -> xh (bf16), 4 elems/thread, exact grid
__global__ __launch_bounds__(256) void k_tobf(const float* __restrict__ x,
                                              u16* __restrict__ xh) {
  int i = blockIdx.x * 256 + threadIdx.x;
  float4 v = ((const float4*)x)[i];
  ushort4 o;
  o.x = f2b(v.x); o.y = f2b(v.y); o.z = f2b(v.z); o.w = f2b(v.w);
  ((ushort4*)xh)[i] = o;
}

// ---- region-sorted CSR build ----

__global__ __launch_bounds__(512) void k_rz(int* __restrict__ rcnt) {
  int t = threadIdx.x;
  if (t < NR + 1) rcnt[t] = 0;
}

// region histogram: 391 blocks x 4096 edges, LDS-local then flush
__global__ __launch_bounds__(256) void k_rhist(const int* __restrict__ ei,
                                               int* __restrict__ rcnt) {
  __shared__ int lh[NR];
  for (int i = threadIdx.x; i < NR; i += 256) lh[i] = 0;
  __syncthreads();
  const int e0 = blockIdx.x * 4096;
  for (int k = 0; k < 16; ++k) {
    int e = e0 + k * 256 + threadIdx.x;
    if (e < NE) atomicAdd(&lh[ei[NE + e] >> 8], 1);
  }
  __syncthreads();
  for (int i = threadIdx.x; i < NR; i += 256)
    if (lh[i]) atomicAdd(&rcnt[i], lh[i]);
}

// scan 391 region counts -> rstart[392]; init cursors; nstartP[NN] = NE
__global__ __launch_bounds__(512) void k_rscan(const int* __restrict__ rcnt,
                                               int* __restrict__ rstart,
                                               int* __restrict__ rcur,
                                               int* __restrict__ nstartP) {
  __shared__ int buf[512];
  const int t = threadIdx.x;
  int v = (t < NR) ? rcnt[t] : 0;
  buf[t] = v;
  __syncthreads();
  for (int off = 1; off < 512; off <<= 1) {
    int u = (t >= off) ? buf[t - off] : 0;
    __syncthreads();
    buf[t] += u;
    __syncthreads();
  }
  if (t < NR) { int s = buf[t] - v; rstart[t] = s; rcur[t] = s; }
  if (t == NR - 1) rstart[NR] = buf[t];  // == NE
  if (t == 0) nstartP[NN] = NE;
}

// scatter packed entries into region segments. ~400 concurrent write fronts,
// each line fills in ~1/256 of kernel lifetime -> full-line evictions.
__global__ __launch_bounds__(256) void k_rfill(const int* __restrict__ ei,
                                               int* __restrict__ rcur,
                                               int* __restrict__ bb) {
  int e = blockIdx.x * 256 + threadIdx.x;
  int src = ei[e];
  int dst = ei[NE + e];
  int p = atomicAdd(&rcur[dst >> 8], 1);
  bb[p] = src | ((dst & 255) << 17);  // src < 2^17, local node in bits 17..24
}

// one block per region: counting-sort region entries by node -> csr2 (global,
// writes stay in a ~16KB L2-resident window) + per-node starts nstartP.
__global__ __launch_bounds__(256) void k_rsort(const int* __restrict__ rstart,
                                               const int* __restrict__ bb,
                                               int* __restrict__ csr2,
                                               int* __restrict__ nstartP) {
  __shared__ int nhist[256], ncur[256], buf[256];
  const int t = threadIdx.x;
  const int r = blockIdx.x;
  const int s = rstart[r];
  const int cnt = rstart[r + 1] - s;
  const int nb = r << 8;
  nhist[t] = 0;
  __syncthreads();
  for (int p = t; p < cnt; p += 256) atomicAdd(&nhist[bb[s + p] >> 17], 1);
  __syncthreads();
  int v = nhist[t];
  buf[t] = v;
  __syncthreads();
  for (int off = 1; off < 256; off <<= 1) {
    int u = (t >= off) ? buf[t - off] : 0;
    __syncthreads();
    buf[t] += u;
    __syncthreads();
  }
  int st = s + buf[t] - v;  // absolute start of node nb+t
  ncur[t] = st;
  if (nb + t < NN) nstartP[nb + t] = st;
  __syncthreads();
  for (int p = t; p < cnt; p += 256) {
    int e2 = bb[s + p];
    int pos = atomicAdd(&ncur[e2 >> 17], 1);
    csr2[pos] = e2 & 0x1FFFF;
  }
}

// ---- fused layer: staged sorted-CSR gather (row-paired, 16 loads in flight)
//      -> f32 LDS tile -> 2-layer MLP -> bf16 out ----
// 4 waves per 64-node tile. Per row: lanes 0-31 even edges, 32-63 odd edges;
// lane accumulates feature pair {2fl, 2fl+1}; combine via shfl_xor(32).
// RACE RULE: xh-in and xh-out must differ.
__global__ __launch_bounds__(256) void k_gin(const u16* __restrict__ xh,
                                             const int* __restrict__ nstartP,
                                             const int* __restrict__ csr2,
                                             const float* __restrict__ eps, int l,
                                             const float* __restrict__ W1,
                                             const float* __restrict__ b1,
                                             const float* __restrict__ W2,
                                             const float* __restrict__ b2,
                                             u16* __restrict__ outh) {
  __shared__ float tile[64 * 65];
  __shared__ int sidx[IDXCAP];
  __shared__ int sstart[65];
  const int tid = threadIdx.x;
  const int lane = tid & 63;
  const int wv = tid >> 6;
  const int h = lane >> 5;
  const int fl = lane & 31;
  const int base = blockIdx.x * 64;
  const int rows = min(64, NN - base);
  const float sc = 1.0f + eps[l];
  const float sch = (h == 0) ? sc : 0.0f;
  const u32* xu = (const u32*)xh;

  const int s0 = nstartP[base];
  const int cnt = nstartP[base + rows] - s0;
  if (tid <= rows) sstart[tid] = nstartP[base + tid];
  const int cs = min(cnt, IDXCAP);
  for (int p = tid; p < cs; p += 256) sidx[p] = csr2[s0 + p];
  __syncthreads();

  if (cnt <= IDXCAP) {
    for (int n = wv; n < rows; n += 8) {
      const int nB = n + 4;
      const bool hasB = nB < rows;
      const int stA = sstart[n];
      const int dA = sstart[n + 1] - stA;
      const int offA = (stA - s0) + h;
      const int mA = (dA + 1 - h) >> 1;
      int offB = 0, mB = 0;
      if (hasB) {
        int stB = sstart[nB];
        int dB = sstart[nB + 1] - stB;
        offB = (stB - s0) + h;
        mB = (dB + 1 - h) >> 1;
      }
      float A0[8], A1[8], B0[8], B1[8];
#pragma unroll
      for (int u = 0; u < 8; ++u) { A0[u] = 0.f; A1[u] = 0.f; B0[u] = 0.f; B1[u] = 0.f; }
      u32 usA = xu[(size_t)(base + n) * 32 + fl];
      A0[0] = sch * blo(usA); A1[0] = sch * bhi(usA);
      if (hasB) {
        u32 usB = xu[(size_t)(base + nB) * 32 + fl];
        B0[0] = sch * blo(usB); B1[0] = sch * bhi(usB);
      }
      float yA0 = 0.f, yA1 = 0.f, yB0 = 0.f, yB1 = 0.f;
      int i = 0;
      const int mMin = hasB ? min(mA, mB) : 0;
      for (; i + 8 <= mMin; i += 8) {  // joint: 16 row-loads in flight
        int ia[8], ib[8];
#pragma unroll
        for (int u = 0; u < 8; ++u) {
          ia[u] = sidx[offA + 2 * (i + u)];
          ib[u] = sidx[offB + 2 * (i + u)];
        }
        u32 va[8], vb[8];
#pragma unroll
        for (int u = 0; u < 8; ++u) {
          va[u] = xu[(size_t)ia[u] * 32 + fl];
          vb[u] = xu[(size_t)ib[u] * 32 + fl];
        }
#pragma unroll
        for (int u = 0; u < 8; ++u) {
          A0[u] += blo(va[u]); A1[u] += bhi(va[u]);
          B0[u] += blo(vb[u]); B1[u] += bhi(vb[u]);
        }
      }
      int iA = i;
      for (; iA + 4 <= mA; iA += 4) {
        int ia[4];
#pragma unroll
        for (int u = 0; u < 4; ++u) ia[u] = sidx[offA + 2 * (iA + u)];
        u32 va[4];
#pragma unroll
        for (int u = 0; u < 4; ++u) va[u] = xu[(size_t)ia[u] * 32 + fl];
#pragma unroll
        for (int u = 0; u < 4; ++u) { A0[u] += blo(va[u]); A1[u] += bhi(va[u]); }
      }
      for (; iA < mA; ++iA) {
        u32 u_ = xu[(size_t)sidx[offA + 2 * iA] * 32 + fl];
        yA0 += blo(u_); yA1 += bhi(u_);
      }
      int iB = i;
      for (; iB + 4 <= mB; iB += 4) {
        int ib[4];
#pragma unroll
        for (int u = 0; u < 4; ++u) ib[u] = sidx[offB + 2 * (iB + u)];
        u32 vb[4];
#pragma unroll
        for (int u = 0; u < 4; ++u) vb[u] = xu[(size_t)ib[u] * 32 + fl];
#pragma unroll
        for (int u = 0; u < 4; ++u) { B0[u] += blo(vb[u]); B1[u] += bhi(vb[u]); }
      }
      for (; iB < mB; ++iB) {
        u32 u_ = xu[(size_t)sidx[offB + 2 * iB] * 32 + fl];
        yB0 += blo(u_); yB1 += bhi(u_);
      }
      float eA0 = (((A0[0] + A0[1]) + (A0[2] + A0[3])) + ((A0[4] + A0[5]) + (A0[6] + A0[7]))) + yA0;
      float eA1 = (((A1[0] + A1[1]) + (A1[2] + A1[3])) + ((A1[4] + A1[5]) + (A1[6] + A1[7]))) + yA1;
      eA0 += __shfl_xor(eA0, 32, 64);
      eA1 += __shfl_xor(eA1, 32, 64);
      if (h == 0) { tile[n * 65 + 2 * fl] = eA0; tile[n * 65 + 2 * fl + 1] = eA1; }
      if (hasB) {
        float eB0 = (((B0[0] + B0[1]) + (B0[2] + B0[3])) + ((B0[4] + B0[5]) + (B0[6] + B0[7]))) + yB0;
        float eB1 = (((B1[0] + B1[1]) + (B1[2] + B1[3])) + ((B1[4] + B1[5]) + (B1[6] + B1[7]))) + yB1;
        eB0 += __shfl_xor(eB0, 32, 64);
        eB1 += __shfl_xor(eB1, 32, 64);
        if (h == 0) { tile[nB * 65 + 2 * fl] = eB0; tile[nB * 65 + 2 * fl + 1] = eB1; }
      }
    }
  } else {
    // fallback (statistically never): indices straight from global csr2
    for (int n = wv; n < rows; n += 4) {
      const int st = sstart[n];
      const int d = sstart[n + 1] - st;
      const int m = (d + 1 - h) >> 1;
      u32 us = xu[(size_t)(base + n) * 32 + fl];
      float e0 = sch * blo(us), e1 = sch * bhi(us);
      for (int i2 = 0; i2 < m; ++i2) {
        u32 u_ = xu[(size_t)csr2[st + h + 2 * i2] * 32 + fl];
        e0 += blo(u_); e1 += bhi(u_);
      }
      e0 += __shfl_xor(e0, 32, 64);
      e1 += __shfl_xor(e1, 32, 64);
      if (h == 0) { tile[n * 65 + 2 * fl] = e0; tile[n * 65 + 2 * fl + 1] = e1; }
    }
  }
  __syncthreads();

  // MLP. lane = node row; wave owns cols [jcs, jcs+16), jcs in SGPR.
  const int jcs = __builtin_amdgcn_readfirstlane(wv * 16);
  float acc[16];
#pragma unroll
  for (int j = 0; j < 16; ++j) acc[j] = b1[jcs + j];
#pragma unroll 4
  for (int k = 0; k < 64; ++k) {
    float a = tile[lane * 65 + k];
#pragma unroll
    for (int j = 0; j < 16; ++j) acc[j] = fmaf(a, W1[k * 64 + jcs + j], acc[j]);
  }
  __syncthreads();
#pragma unroll
  for (int j = 0; j < 16; ++j) tile[lane * 65 + jcs + j] = fmaxf(acc[j], 0.0f);
  __syncthreads();

#pragma unroll
  for (int j = 0; j < 16; ++j) acc[j] = b2[jcs + j];
#pragma unroll 4
  for (int k = 0; k < 64; ++k) {
    float a = tile[lane * 65 + k];
#pragma unroll
    for (int j = 0; j < 16; ++j) acc[j] = fmaf(a, W2[k * 64 + jcs + j], acc[j]);
  }
  __syncthreads();
#pragma unroll
  for (int j = 0; j < 16; ++j) tile[lane * 65 + jcs + j] = fmaxf(acc[j], 0.0f);
  __syncthreads();

  for (int n = wv; n < rows; n += 4)
    outh[(size_t)(base + n) * DIM + lane] = f2b(tile[n * 65 + lane]);
}

// out(f32) = bf16_in @ Wf + bf
__global__ __launch_bounds__(256) void k_final(const u16* __restrict__ in,
                                               const float* __restrict__ Wf,
                                               const float* __restrict__ bf,
                                               float* __restrict__ out) {
  __shared__ float tile[64 * 65];
  const int lane = threadIdx.x & 63;
  const int wv = threadIdx.x >> 6;
  const int base = blockIdx.x * 64;
  const int rows = min(64, NN - base);
  const int jcs = __builtin_amdgcn_readfirstlane(wv * 16);

  for (int n = wv; n < rows; n += 4)
    tile[n * 65 + lane] = b2f(in[(size_t)(base + n) * DIM + lane]);
  __syncthreads();

  float acc[16];
#pragma unroll
  for (int j = 0; j < 16; ++j) acc[j] = bf[jcs + j];
#pragma unroll 4
  for (int k = 0; k < 64; ++k) {
    float a = tile[lane * 65 + k];
#pragma unroll
    for (int j = 0; j < 16; ++j) acc[j] = fmaf(a, Wf[k * 64 + jcs + j], acc[j]);
  }
  __syncthreads();
#pragma unroll
  for (int j = 0; j < 16; ++j) tile[lane * 65 + jcs + j] = acc[j];
  __syncthreads();

  for (int n = wv; n < rows; n += 4)
    out[(size_t)(base + n) * DIM + lane] = tile[n * 65 + lane];
}

extern "C" void kernel_launch(void* const* d_in, const int* in_sizes, int n_in,
                              void* d_out, int out_size, void* d_ws, size_t ws_size,
                              hipStream_t stream) {
  const float* x   = (const float*)d_in[0];
  const int*   ei  = (const int*)d_in[1];
  const float* W1  = (const float*)d_in[2];
  const float* b1  = (const float*)d_in[3];
  const float* W2  = (const float*)d_in[4];
  const float* b2  = (const float*)d_in[5];
  const float* eps = (const float*)d_in[6];
  const float* Wf  = (const float*)d_in[7];
  const float* bf  = (const float*)d_in[8];

  // ws: xh0 | xh1 [NN*64 u16 each, 12.8MB] | csr2[NE, 6.4MB] | nstartP[NN+1]
  //     | rcnt[NR+1] | rstart[NR+1] | rcur[NR]   (~32.4 MB)
  u16* xh0 = (u16*)d_ws;
  u16* xh1 = xh0 + (size_t)NN * DIM;
  int* csr2    = (int*)(xh1 + (size_t)NN * DIM);
  int* nstartP = csr2 + NE;
  int* rcnt    = nstartP + NN + 1;
  int* rstart  = rcnt + NR + 1;
  int* rcur    = rstart + NR + 1;
  // bb lives in d_out (dead until k_final writes it at the end)
  int* bb = (int*)d_out;

  const int grid_conv = NN * DIM / 4 / 256;  // 6250, exact
  const int grid_fill = NE / 256;            // 6250, exact
  const int grid_mlp  = (NN + 63) / 64;      // 1563

  k_tobf<<<grid_conv, 256, 0, stream>>>(x, xh0);
  k_rz<<<1, 512, 0, stream>>>(rcnt);
  k_rhist<<<NR, 256, 0, stream>>>(ei, rcnt);
  k_rscan<<<1, 512, 0, stream>>>(rcnt, rstart, rcur, nstartP);
  k_rfill<<<grid_fill, 256, 0, stream>>>(ei, rcur, bb);
  k_rsort<<<NR, 256, 0, stream>>>(rstart, bb, csr2, nstartP);

  // bf16 ping-pong: L0 xh0->xh1, L1 xh1->xh0, L2 xh0->xh1, final xh1->d_out
  k_gin<<<grid_mlp, 256, 0, stream>>>(xh0, nstartP, csr2, eps, 0,
                                      W1, b1, W2, b2, xh1);
  k_gin<<<grid_mlp, 256, 0, stream>>>(xh1, nstartP, csr2, eps, 1,
                                      W1 + 64 * 64, b1 + 64, W2 + 64 * 64, b2 + 64, xh0);
  k_gin<<<grid_mlp, 256, 0, stream>>>(xh0, nstartP, csr2, eps, 2,
                                      W1 + 2 * 64 * 64, b1 + 2 * 64, W2 + 2 * 64 * 64, b2 + 2 * 64, xh1);
  k_final<<<grid_mlp, 256, 0, stream>>>(xh1, Wf, bf, (float*)d_out);
}

// Round 9
// 338.373 us; speedup vs baseline: 2.6250x; 2.6250x over previous
//
#include <hip/hip_runtime.h>

#define NN 100000
#define NE 1600000
#define DIM 64
#define NR 391      // regions = ceil(NN/256), key = dst>>8
#define BP 400      // partition blocks, 4000 edges each
#define MH (NR * BP)  // 156400 histogram cells, r-major
#define NSB2 611    // ceil(MH/256)
#define IDXCAP 2048 // LDS-staged csr2 slice cap per 64-node tile (mean 1024, 32 sigma)

typedef unsigned short u16;
typedef unsigned int u32;

__device__ __forceinline__ u16 f2b(float f) {  // f32 -> bf16 RNE
  union { float f; u32 u; } c; c.f = f;
  u32 u = c.u;
  u += 0x7FFF + ((u >> 16) & 1);
  return (u16)(u >> 16);
}
__device__ __forceinline__ float b2f(u16 h) {
  union { u32 u; float f; } c; c.u = ((u32)h) << 16;
  return c.f;
}
__device__ __forceinline__ float blo(u32 v) {
  union { u32 u; float f; } c; c.u = v << 16;
  return c.f;
}
__device__ __forceinline__ float bhi(u32 v) {
  union { u32 u; float f; } c; c.u = v & 0xFFFF0000u;
  return c.f;
}

// x (f32) -> xh (bf16), 4 elems/thread, exact grid
__global__ __launch_bounds__(256) void k_tobf(const float* __restrict__ x,
                                              u16* __restrict__ xh) {
  int i = blockIdx.x * 256 + threadIdx.x;
  float4 v = ((const float4*)x)[i];
  ushort4 o;
  o.x = f2b(v.x); o.y = f2b(v.y); o.z = f2b(v.z); o.w = f2b(v.w);
  ((ushort4*)xh)[i] = o;
}

// ---- deterministic two-pass region partition (no global data atomics) ----

// pass 1: per-block region histogram in LDS -> H[r][b] (every cell written)
__global__ __launch_bounds__(256) void k_phist(const int* __restrict__ ei,
                                               int* __restrict__ Hmat) {
  __shared__ int lh[NR];
  const int t = threadIdx.x;
  const int b = blockIdx.x;
  for (int i = t; i < NR; i += 256) lh[i] = 0;
  __syncthreads();
  const int e0 = b * 4000;
  for (int k = 0; k < 16; ++k) {
    int o = k * 256 + t;
    if (o < 4000) atomicAdd(&lh[ei[NE + e0 + o] >> 8], 1);
  }
  __syncthreads();
  for (int i = t; i < NR; i += 256) Hmat[i * BP + b] = lh[i];
}

// flat exclusive scan of Hmat[MH]: per-block scan -> block sums
__global__ __launch_bounds__(256) void k_sA(int* __restrict__ a,
                                            int* __restrict__ bsum) {
  __shared__ int buf[256];
  const int t = threadIdx.x;
  const int i = blockIdx.x * 256 + t;
  int v = (i < MH) ? a[i] : 0;
  buf[t] = v;
  __syncthreads();
  for (int off = 1; off < 256; off <<= 1) {
    int u = (t >= off) ? buf[t - off] : 0;
    __syncthreads();
    buf[t] += u;
    __syncthreads();
  }
  if (i < MH) a[i] = buf[t] - v;
  if (t == 255) bsum[blockIdx.x] = buf[255];
}

// scan the 611 block sums in place (exclusive)
__global__ __launch_bounds__(1024) void k_sB(int* __restrict__ bsum) {
  __shared__ int buf[1024];
  const int t = threadIdx.x;
  int v = (t < NSB2) ? bsum[t] : 0;
  buf[t] = v;
  __syncthreads();
  for (int off = 1; off < 1024; off <<= 1) {
    int u = (t >= off) ? buf[t - off] : 0;
    __syncthreads();
    buf[t] += u;
    __syncthreads();
  }
  if (t < NSB2) bsum[t] = buf[t] - v;
}

__global__ __launch_bounds__(256) void k_sC(int* __restrict__ a,
                                            const int* __restrict__ bsum) {
  int i = blockIdx.x * 256 + threadIdx.x;
  if (i < MH) a[i] += bsum[blockIdx.x];
}

// extract region starts from scanned H; set sentinels
__global__ __launch_bounds__(512) void k_rex(const int* __restrict__ Hs,
                                             int* __restrict__ rstart,
                                             int* __restrict__ nstartP) {
  int t = threadIdx.x;
  if (t < NR) rstart[t] = Hs[t * BP];
  if (t == 0) { rstart[NR] = NE; nstartP[NN] = NE; }
}

// pass 2: scatter with LDS cursors (H[r][b] = this block's exclusive slot
// base in region r). Each (block,region) group writes CONSECUTIVE words.
__global__ __launch_bounds__(256) void k_pfill(const int* __restrict__ ei,
                                               const int* __restrict__ Hs,
                                               int* __restrict__ bb) {
  __shared__ int lcur[NR];
  const int t = threadIdx.x;
  const int b = blockIdx.x;
  for (int i = t; i < NR; i += 256) lcur[i] = Hs[i * BP + b];
  __syncthreads();
  const int e0 = b * 4000;
  for (int k = 0; k < 16; ++k) {
    int o = k * 256 + t;
    if (o < 4000) {
      int e = e0 + o;
      int src = ei[e];
      int dst = ei[NE + e];
      int p = atomicAdd(&lcur[dst >> 8], 1);  // LDS atomic only
      bb[p] = src | ((dst & 255) << 17);      // src < 2^17
    }
  }
}

// one block per region: counting-sort region entries by node -> csr2 (writes
// stay in a ~16KB L2-resident window) + per-node starts nstartP.
__global__ __launch_bounds__(256) void k_rsort(const int* __restrict__ rstart,
                                               const int* __restrict__ bb,
                                               int* __restrict__ csr2,
                                               int* __restrict__ nstartP) {
  __shared__ int nhist[256], ncur[256], buf[256];
  const int t = threadIdx.x;
  const int r = blockIdx.x;
  const int s = rstart[r];
  const int cnt = rstart[r + 1] - s;
  const int nb = r << 8;
  nhist[t] = 0;
  __syncthreads();
  for (int p = t; p < cnt; p += 256) atomicAdd(&nhist[bb[s + p] >> 17], 1);
  __syncthreads();
  int v = nhist[t];
  buf[t] = v;
  __syncthreads();
  for (int off = 1; off < 256; off <<= 1) {
    int u = (t >= off) ? buf[t - off] : 0;
    __syncthreads();
    buf[t] += u;
    __syncthreads();
  }
  int st = s + buf[t] - v;  // absolute start of node nb+t
  ncur[t] = st;
  if (nb + t < NN) nstartP[nb + t] = st;
  __syncthreads();
  for (int p = t; p < cnt; p += 256) {
    int e2 = bb[s + p];
    int pos = atomicAdd(&ncur[e2 >> 17], 1);
    csr2[pos] = e2 & 0x1FFFF;
  }
}

// ---- fused layer: staged sorted-CSR gather (row-paired, 16 loads in flight)
//      -> f32 LDS tile -> 2-layer MLP -> bf16 out ----
// 4 waves per 64-node tile. Per row: lanes 0-31 even edges, 32-63 odd edges;
// lane accumulates feature pair {2fl, 2fl+1}; combine via shfl_xor(32).
// RACE RULE: xh-in and xh-out must differ.
__global__ __launch_bounds__(256) void k_gin(const u16* __restrict__ xh,
                                             const int* __restrict__ nstartP,
                                             const int* __restrict__ csr2,
                                             const float* __restrict__ eps, int l,
                                             const float* __restrict__ W1,
                                             const float* __restrict__ b1,
                                             const float* __restrict__ W2,
                                             const float* __restrict__ b2,
                                             u16* __restrict__ outh) {
  __shared__ float tile[64 * 65];
  __shared__ int sidx[IDXCAP];
  __shared__ int sstart[65];
  const int tid = threadIdx.x;
  const int lane = tid & 63;
  const int wv = tid >> 6;
  const int h = lane >> 5;
  const int fl = lane & 31;
  const int base = blockIdx.x * 64;
  const int rows = min(64, NN - base);
  const float sc = 1.0f + eps[l];
  const float sch = (h == 0) ? sc : 0.0f;
  const u32* xu = (const u32*)xh;

  const int s0 = nstartP[base];
  const int cnt = nstartP[base + rows] - s0;
  if (tid <= rows) sstart[tid] = nstartP[base + tid];
  const int cs = min(cnt, IDXCAP);
  for (int p = tid; p < cs; p += 256) sidx[p] = csr2[s0 + p];
  __syncthreads();

  if (cnt <= IDXCAP) {
    for (int n = wv; n < rows; n += 8) {
      const int nB = n + 4;
      const bool hasB = nB < rows;
      const int stA = sstart[n];
      const int dA = sstart[n + 1] - stA;
      const int offA = (stA - s0) + h;
      const int mA = (dA + 1 - h) >> 1;
      int offB = 0, mB = 0;
      if (hasB) {
        int stB = sstart[nB];
        int dB = sstart[nB + 1] - stB;
        offB = (stB - s0) + h;
        mB = (dB + 1 - h) >> 1;
      }
      float A0[8], A1[8], B0[8], B1[8];
#pragma unroll
      for (int u = 0; u < 8; ++u) { A0[u] = 0.f; A1[u] = 0.f; B0[u] = 0.f; B1[u] = 0.f; }
      u32 usA = xu[(size_t)(base + n) * 32 + fl];
      A0[0] = sch * blo(usA); A1[0] = sch * bhi(usA);
      if (hasB) {
        u32 usB = xu[(size_t)(base + nB) * 32 + fl];
        B0[0] = sch * blo(usB); B1[0] = sch * bhi(usB);
      }
      float yA0 = 0.f, yA1 = 0.f, yB0 = 0.f, yB1 = 0.f;
      int i = 0;
      const int mMin = hasB ? min(mA, mB) : 0;
      for (; i + 8 <= mMin; i += 8) {  // joint: 16 row-loads in flight
        int ia[8], ib[8];
#pragma unroll
        for (int u = 0; u < 8; ++u) {
          ia[u] = sidx[offA + 2 * (i + u)];
          ib[u] = sidx[offB + 2 * (i + u)];
        }
        u32 va[8], vb[8];
#pragma unroll
        for (int u = 0; u < 8; ++u) {
          va[u] = xu[(size_t)ia[u] * 32 + fl];
          vb[u] = xu[(size_t)ib[u] * 32 + fl];
        }
#pragma unroll
        for (int u = 0; u < 8; ++u) {
          A0[u] += blo(va[u]); A1[u] += bhi(va[u]);
          B0[u] += blo(vb[u]); B1[u] += bhi(vb[u]);
        }
      }
      int iA = i;
      for (; iA + 4 <= mA; iA += 4) {
        int ia[4];
#pragma unroll
        for (int u = 0; u < 4; ++u) ia[u] = sidx[offA + 2 * (iA + u)];
        u32 va[4];
#pragma unroll
        for (int u = 0; u < 4; ++u) va[u] = xu[(size_t)ia[u] * 32 + fl];
#pragma unroll
        for (int u = 0; u < 4; ++u) { A0[u] += blo(va[u]); A1[u] += bhi(va[u]); }
      }
      for (; iA < mA; ++iA) {
        u32 u_ = xu[(size_t)sidx[offA + 2 * iA] * 32 + fl];
        yA0 += blo(u_); yA1 += bhi(u_);
      }
      int iB = i;
      for (; iB + 4 <= mB; iB += 4) {
        int ib[4];
#pragma unroll
        for (int u = 0; u < 4; ++u) ib[u] = sidx[offB + 2 * (iB + u)];
        u32 vb[4];
#pragma unroll
        for (int u = 0; u < 4; ++u) vb[u] = xu[(size_t)ib[u] * 32 + fl];
#pragma unroll
        for (int u = 0; u < 4; ++u) { B0[u] += blo(vb[u]); B1[u] += bhi(vb[u]); }
      }
      for (; iB < mB; ++iB) {
        u32 u_ = xu[(size_t)sidx[offB + 2 * iB] * 32 + fl];
        yB0 += blo(u_); yB1 += bhi(u_);
      }
      float eA0 = (((A0[0] + A0[1]) + (A0[2] + A0[3])) + ((A0[4] + A0[5]) + (A0[6] + A0[7]))) + yA0;
      float eA1 = (((A1[0] + A1[1]) + (A1[2] + A1[3])) + ((A1[4] + A1[5]) + (A1[6] + A1[7]))) + yA1;
      eA0 += __shfl_xor(eA0, 32, 64);
      eA1 += __shfl_xor(eA1, 32, 64);
      if (h == 0) { tile[n * 65 + 2 * fl] = eA0; tile[n * 65 + 2 * fl + 1] = eA1; }
      if (hasB) {
        float eB0 = (((B0[0] + B0[1]) + (B0[2] + B0[3])) + ((B0[4] + B0[5]) + (B0[6] + B0[7]))) + yB0;
        float eB1 = (((B1[0] + B1[1]) + (B1[2] + B1[3])) + ((B1[4] + B1[5]) + (B1[6] + B1[7]))) + yB1;
        eB0 += __shfl_xor(eB0, 32, 64);
        eB1 += __shfl_xor(eB1, 32, 64);
        if (h == 0) { tile[nB * 65 + 2 * fl] = eB0; tile[nB * 65 + 2 * fl + 1] = eB1; }
      }
    }
  } else {
    // fallback (statistically never): indices straight from global csr2
    for (int n = wv; n < rows; n += 4) {
      const int st = sstart[n];
      const int d = sstart[n + 1] - st;
      const int m = (d + 1 - h) >> 1;
      u32 us = xu[(size_t)(base + n) * 32 + fl];
      float e0 = sch * blo(us), e1 = sch * bhi(us);
      for (int i2 = 0; i2 < m; ++i2) {
        u32 u_ = xu[(size_t)csr2[st + h + 2 * i2] * 32 + fl];
        e0 += blo(u_); e1 += bhi(u_);
      }
      e0 += __shfl_xor(e0, 32, 64);
      e1 += __shfl_xor(e1, 32, 64);
      if (h == 0) { tile[n * 65 + 2 * fl] = e0; tile[n * 65 + 2 * fl + 1] = e1; }
    }
  }
  __syncthreads();

  // MLP. lane = node row; wave owns cols [jcs, jcs+16), jcs in SGPR.
  const int jcs = __builtin_amdgcn_readfirstlane(wv * 16);
  float acc[16];
#pragma unroll
  for (int j = 0; j < 16; ++j) acc[j] = b1[jcs + j];
#pragma unroll 4
  for (int k = 0; k < 64; ++k) {
    float a = tile[lane * 65 + k];
#pragma unroll
    for (int j = 0; j < 16; ++j) acc[j] = fmaf(a, W1[k * 64 + jcs + j], acc[j]);
  }
  __syncthreads();
#pragma unroll
  for (int j = 0; j < 16; ++j) tile[lane * 65 + jcs + j] = fmaxf(acc[j], 0.0f);
  __syncthreads();

#pragma unroll
  for (int j = 0; j < 16; ++j) acc[j] = b2[jcs + j];
#pragma unroll 4
  for (int k = 0; k < 64; ++k) {
    float a = tile[lane * 65 + k];
#pragma unroll
    for (int j = 0; j < 16; ++j) acc[j] = fmaf(a, W2[k * 64 + jcs + j], acc[j]);
  }
  __syncthreads();
#pragma unroll
  for (int j = 0; j < 16; ++j) tile[lane * 65 + jcs + j] = fmaxf(acc[j], 0.0f);
  __syncthreads();

  for (int n = wv; n < rows; n += 4)
    outh[(size_t)(base + n) * DIM + lane] = f2b(tile[n * 65 + lane]);
}

// out(f32) = bf16_in @ Wf + bf
__global__ __launch_bounds__(256) void k_final(const u16* __restrict__ in,
                                               const float* __restrict__ Wf,
                                               const float* __restrict__ bf,
                                               float* __restrict__ out) {
  __shared__ float tile[64 * 65];
  const int lane = threadIdx.x & 63;
  const int wv = threadIdx.x >> 6;
  const int base = blockIdx.x * 64;
  const int rows = min(64, NN - base);
  const int jcs = __builtin_amdgcn_readfirstlane(wv * 16);

  for (int n = wv; n < rows; n += 4)
    tile[n * 65 + lane] = b2f(in[(size_t)(base + n) * DIM + lane]);
  __syncthreads();

  float acc[16];
#pragma unroll
  for (int j = 0; j < 16; ++j) acc[j] = bf[jcs + j];
#pragma unroll 4
  for (int k = 0; k < 64; ++k) {
    float a = tile[lane * 65 + k];
#pragma unroll
    for (int j = 0; j < 16; ++j) acc[j] = fmaf(a, Wf[k * 64 + jcs + j], acc[j]);
  }
  __syncthreads();
#pragma unroll
  for (int j = 0; j < 16; ++j) tile[lane * 65 + jcs + j] = acc[j];
  __syncthreads();

  for (int n = wv; n < rows; n += 4)
    out[(size_t)(base + n) * DIM + lane] = tile[n * 65 + lane];
}

extern "C" void kernel_launch(void* const* d_in, const int* in_sizes, int n_in,
                              void* d_out, int out_size, void* d_ws, size_t ws_size,
                              hipStream_t stream) {
  const float* x   = (const float*)d_in[0];
  const int*   ei  = (const int*)d_in[1];
  const float* W1  = (const float*)d_in[2];
  const float* b1  = (const float*)d_in[3];
  const float* W2  = (const float*)d_in[4];
  const float* b2  = (const float*)d_in[5];
  const float* eps = (const float*)d_in[6];
  const float* Wf  = (const float*)d_in[7];
  const float* bf  = (const float*)d_in[8];

  // ws: xh0 | xh1 [NN*64 u16 each, 12.8MB] | csr2[NE, 6.4MB] | nstartP[NN+1]
  //     | Hmat[MH, 626KB] | bsum[NSB2] | rstart[NR+1]   (~33.1 MB)
  u16* xh0 = (u16*)d_ws;
  u16* xh1 = xh0 + (size_t)NN * DIM;
  int* csr2    = (int*)(xh1 + (size_t)NN * DIM);
  int* nstartP = csr2 + NE;
  int* Hmat    = nstartP + NN + 1;
  int* bsum    = Hmat + MH;
  int* rstart  = bsum + NSB2;
  // bb lives in d_out (dead until k_final writes it at the end)
  int* bb = (int*)d_out;

  const int grid_conv = NN * DIM / 4 / 256;  // 6250, exact
  const int grid_mlp  = (NN + 63) / 64;      // 1563

  k_tobf<<<grid_conv, 256, 0, stream>>>(x, xh0);
  k_phist<<<BP, 256, 0, stream>>>(ei, Hmat);
  k_sA<<<NSB2, 256, 0, stream>>>(Hmat, bsum);
  k_sB<<<1, 1024, 0, stream>>>(bsum);
  k_sC<<<NSB2, 256, 0, stream>>>(Hmat, bsum);
  k_rex<<<1, 512, 0, stream>>>(Hmat, rstart, nstartP);
  k_pfill<<<BP, 256, 0, stream>>>(ei, Hmat, bb);
  k_rsort<<<NR, 256, 0, stream>>>(rstart, bb, csr2, nstartP);

  // bf16 ping-pong: L0 xh0->xh1, L1 xh1->xh0, L2 xh0->xh1, final xh1->d_out
  k_gin<<<grid_mlp, 256, 0, stream>>>(xh0, nstartP, csr2, eps, 0,
                                      W1, b1, W2, b2, xh1);
  k_gin<<<grid_mlp, 256, 0, stream>>>(xh1, nstartP, csr2, eps, 1,
                                      W1 + 64 * 64, b1 + 64, W2 + 64 * 64, b2 + 64, xh0);
  k_gin<<<grid_mlp, 256, 0, stream>>>(xh0, nstartP, csr2, eps, 2,
                                      W1 + 2 * 64 * 64, b1 + 2 * 64, W2 + 2 * 64 * 64, b2 + 2 * 64, xh1);
  k_final<<<grid_mlp, 256, 0, stream>>>(xh1, Wf, bf, (float*)d_out);
}

// Round 10
// 301.695 us; speedup vs baseline: 2.9441x; 1.1216x over previous
//
#include <hip/hip_runtime.h>

#define NN 100000
#define NE 1600000
#define DIM 64
#define NR 391      // regions = ceil(NN/256), key = dst>>8
#define BP 400      // partition blocks, 4000 edges each
#define MH (NR * BP)  // 156400 histogram cells, r-major
#define NSB2 611    // ceil(MH/256)
#define IDXCAP 1536 // LDS-staged csr2 slice cap per 64-node tile (mean 1024, 16 sigma)

typedef unsigned short u16;
typedef unsigned int u32;

__device__ __forceinline__ u16 f2b(float f) {  // f32 -> bf16 RNE
  union { float f; u32 u; } c; c.f = f;
  u32 u = c.u;
  u += 0x7FFF + ((u >> 16) & 1);
  return (u16)(u >> 16);
}
__device__ __forceinline__ float b2f(u16 h) {
  union { u32 u; float f; } c; c.u = ((u32)h) << 16;
  return c.f;
}
__device__ __forceinline__ float blo(u32 v) {
  union { u32 u; float f; } c; c.u = v << 16;
  return c.f;
}
__device__ __forceinline__ float bhi(u32 v) {
  union { u32 u; float f; } c; c.u = v & 0xFFFF0000u;
  return c.f;
}
__device__ __forceinline__ u32 pk(float lo, float hi) {  // pack 2 bf16
  return ((u32)f2b(hi) << 16) | (u32)f2b(lo);
}

// x (f32) -> xh (bf16), 4 elems/thread, exact grid
__global__ __launch_bounds__(256) void k_tobf(const float* __restrict__ x,
                                              u16* __restrict__ xh) {
  int i = blockIdx.x * 256 + threadIdx.x;
  float4 v = ((const float4*)x)[i];
  ushort4 o;
  o.x = f2b(v.x); o.y = f2b(v.y); o.z = f2b(v.z); o.w = f2b(v.w);
  ((ushort4*)xh)[i] = o;
}

// ---- deterministic two-pass region partition (no global data atomics) ----

// pass 1: per-block region histogram in LDS -> H[r][b]
__global__ __launch_bounds__(256) void k_phist(const int* __restrict__ ei,
                                               int* __restrict__ Hmat) {
  __shared__ int lh[NR];
  const int t = threadIdx.x;
  const int b = blockIdx.x;
  for (int i = t; i < NR; i += 256) lh[i] = 0;
  __syncthreads();
  const int e0 = b * 4000;
  for (int k = 0; k < 16; ++k) {
    int o = k * 256 + t;
    if (o < 4000) atomicAdd(&lh[ei[NE + e0 + o] >> 8], 1);
  }
  __syncthreads();
  for (int i = t; i < NR; i += 256) Hmat[i * BP + b] = lh[i];
}

// flat exclusive scan of Hmat[MH]: per-block scan -> block sums
__global__ __launch_bounds__(256) void k_sA(int* __restrict__ a,
                                            int* __restrict__ bsum) {
  __shared__ int buf[256];
  const int t = threadIdx.x;
  const int i = blockIdx.x * 256 + t;
  int v = (i < MH) ? a[i] : 0;
  buf[t] = v;
  __syncthreads();
  for (int off = 1; off < 256; off <<= 1) {
    int u = (t >= off) ? buf[t - off] : 0;
    __syncthreads();
    buf[t] += u;
    __syncthreads();
  }
  if (i < MH) a[i] = buf[t] - v;
  if (t == 255) bsum[blockIdx.x] = buf[255];
}

// scan the 611 block sums in place (exclusive)
__global__ __launch_bounds__(1024) void k_sB(int* __restrict__ bsum) {
  __shared__ int buf[1024];
  const int t = threadIdx.x;
  int v = (t < NSB2) ? bsum[t] : 0;
  buf[t] = v;
  __syncthreads();
  for (int off = 1; off < 1024; off <<= 1) {
    int u = (t >= off) ? buf[t - off] : 0;
    __syncthreads();
    buf[t] += u;
    __syncthreads();
  }
  if (t < NSB2) bsum[t] = buf[t] - v;
}

__global__ __launch_bounds__(256) void k_sC(int* __restrict__ a,
                                            const int* __restrict__ bsum) {
  int i = blockIdx.x * 256 + threadIdx.x;
  if (i < MH) a[i] += bsum[blockIdx.x];
}

// extract region starts from scanned H; set sentinels
__global__ __launch_bounds__(512) void k_rex(const int* __restrict__ Hs,
                                             int* __restrict__ rstart,
                                             int* __restrict__ nstartP) {
  int t = threadIdx.x;
  if (t < NR) rstart[t] = Hs[t * BP];
  if (t == 0) { rstart[NR] = NE; nstartP[NN] = NE; }
}

// pass 2: scatter with LDS cursors; (block,region) groups write consecutively
__global__ __launch_bounds__(256) void k_pfill(const int* __restrict__ ei,
                                               const int* __restrict__ Hs,
                                               int* __restrict__ bb) {
  __shared__ int lcur[NR];
  const int t = threadIdx.x;
  const int b = blockIdx.x;
  for (int i = t; i < NR; i += 256) lcur[i] = Hs[i * BP + b];
  __syncthreads();
  const int e0 = b * 4000;
  for (int k = 0; k < 16; ++k) {
    int o = k * 256 + t;
    if (o < 4000) {
      int e = e0 + o;
      int src = ei[e];
      int dst = ei[NE + e];
      int p = atomicAdd(&lcur[dst >> 8], 1);  // LDS atomic only
      bb[p] = src | ((dst & 255) << 17);      // src < 2^17
    }
  }
}

// one block per region: counting-sort region entries by node -> csr2 + nstartP
__global__ __launch_bounds__(256) void k_rsort(const int* __restrict__ rstart,
                                               const int* __restrict__ bb,
                                               int* __restrict__ csr2,
                                               int* __restrict__ nstartP) {
  __shared__ int nhist[256], ncur[256], buf[256];
  const int t = threadIdx.x;
  const int r = blockIdx.x;
  const int s = rstart[r];
  const int cnt = rstart[r + 1] - s;
  const int nb = r << 8;
  nhist[t] = 0;
  __syncthreads();
  for (int p = t; p < cnt; p += 256) atomicAdd(&nhist[bb[s + p] >> 17], 1);
  __syncthreads();
  int v = nhist[t];
  buf[t] = v;
  __syncthreads();
  for (int off = 1; off < 256; off <<= 1) {
    int u = (t >= off) ? buf[t - off] : 0;
    __syncthreads();
    buf[t] += u;
    __syncthreads();
  }
  int st = s + buf[t] - v;  // absolute start of node nb+t
  ncur[t] = st;
  if (nb + t < NN) nstartP[nb + t] = st;
  __syncthreads();
  for (int p = t; p < cnt; p += 256) {
    int e2 = bb[s + p];
    int pos = atomicAdd(&ncur[e2 >> 17], 1);
    csr2[pos] = e2 & 0x1FFFF;
  }
}

// ---- fused layer: staged sorted-CSR gather (row-paired, 16 loads in flight)
//      -> bf16-packed LDS tile -> 2-layer MLP (f32 acc) -> bf16 out ----
// LDS ~14.9KB -> 8 blocks/CU (32 waves, wave-capped). __launch_bounds__(256,8)
// pins VGPR<=64 for the 8-wave/SIMD occupancy.
__global__ __launch_bounds__(256, 8) void k_gin(const u16* __restrict__ xh,
                                                const int* __restrict__ nstartP,
                                                const int* __restrict__ csr2,
                                                const float* __restrict__ eps, int l,
                                                const float* __restrict__ W1,
                                                const float* __restrict__ b1,
                                                const float* __restrict__ W2,
                                                const float* __restrict__ b2,
                                                u16* __restrict__ outh) {
  __shared__ u32 tile32[64 * 33];  // bf16 pair per cell; row stride 33 -> 2-way banks
  __shared__ int sidx[IDXCAP];
  __shared__ int sstart[65];
  const int tid = threadIdx.x;
  const int lane = tid & 63;
  const int wv = tid >> 6;
  const int h = lane >> 5;
  const int fl = lane & 31;
  const int base = blockIdx.x * 64;
  const int rows = min(64, NN - base);
  const float sc = 1.0f + eps[l];
  const float sch = (h == 0) ? sc : 0.0f;
  const u32* xu = (const u32*)xh;

  const int s0 = nstartP[base];
  const int cnt = nstartP[base + rows] - s0;
  if (tid <= rows) sstart[tid] = nstartP[base + tid];
  const int cs = min(cnt, IDXCAP);
  for (int p = tid; p < cs; p += 256) sidx[p] = csr2[s0 + p];
  __syncthreads();

  if (cnt <= IDXCAP) {
    for (int n = wv; n < rows; n += 8) {
      const int nB = n + 4;
      const bool hasB = nB < rows;
      const int stA = sstart[n];
      const int dA = sstart[n + 1] - stA;
      const int offA = (stA - s0) + h;
      const int mA = (dA + 1 - h) >> 1;
      int offB = 0, mB = 0;
      if (hasB) {
        int stB = sstart[nB];
        int dB = sstart[nB + 1] - stB;
        offB = (stB - s0) + h;
        mB = (dB + 1 - h) >> 1;
      }
      float A0[8], A1[8], B0[8], B1[8];
#pragma unroll
      for (int u = 0; u < 8; ++u) { A0[u] = 0.f; A1[u] = 0.f; B0[u] = 0.f; B1[u] = 0.f; }
      u32 usA = xu[(size_t)(base + n) * 32 + fl];
      A0[0] = sch * blo(usA); A1[0] = sch * bhi(usA);
      if (hasB) {
        u32 usB = xu[(size_t)(base + nB) * 32 + fl];
        B0[0] = sch * blo(usB); B1[0] = sch * bhi(usB);
      }
      float yA0 = 0.f, yA1 = 0.f, yB0 = 0.f, yB1 = 0.f;
      int i = 0;
      const int mMin = hasB ? min(mA, mB) : 0;
      for (; i + 8 <= mMin; i += 8) {  // joint: 16 row-loads in flight
        int ia[8], ib[8];
#pragma unroll
        for (int u = 0; u < 8; ++u) {
          ia[u] = sidx[offA + 2 * (i + u)];
          ib[u] = sidx[offB + 2 * (i + u)];
        }
        u32 va[8], vb[8];
#pragma unroll
        for (int u = 0; u < 8; ++u) {
          va[u] = xu[(size_t)ia[u] * 32 + fl];
          vb[u] = xu[(size_t)ib[u] * 32 + fl];
        }
#pragma unroll
        for (int u = 0; u < 8; ++u) {
          A0[u] += blo(va[u]); A1[u] += bhi(va[u]);
          B0[u] += blo(vb[u]); B1[u] += bhi(vb[u]);
        }
      }
      int iA = i;
      for (; iA + 4 <= mA; iA += 4) {
        int ia[4];
#pragma unroll
        for (int u = 0; u < 4; ++u) ia[u] = sidx[offA + 2 * (iA + u)];
        u32 va[4];
#pragma unroll
        for (int u = 0; u < 4; ++u) va[u] = xu[(size_t)ia[u] * 32 + fl];
#pragma unroll
        for (int u = 0; u < 4; ++u) { A0[u] += blo(va[u]); A1[u] += bhi(va[u]); }
      }
      for (; iA < mA; ++iA) {
        u32 u_ = xu[(size_t)sidx[offA + 2 * iA] * 32 + fl];
        yA0 += blo(u_); yA1 += bhi(u_);
      }
      int iB = i;
      for (; iB + 4 <= mB; iB += 4) {
        int ib[4];
#pragma unroll
        for (int u = 0; u < 4; ++u) ib[u] = sidx[offB + 2 * (iB + u)];
        u32 vb[4];
#pragma unroll
        for (int u = 0; u < 4; ++u) vb[u] = xu[(size_t)ib[u] * 32 + fl];
#pragma unroll
        for (int u = 0; u < 4; ++u) { B0[u] += blo(vb[u]); B1[u] += bhi(vb[u]); }
      }
      for (; iB < mB; ++iB) {
        u32 u_ = xu[(size_t)sidx[offB + 2 * iB] * 32 + fl];
        yB0 += blo(u_); yB1 += bhi(u_);
      }
      float eA0 = (((A0[0] + A0[1]) + (A0[2] + A0[3])) + ((A0[4] + A0[5]) + (A0[6] + A0[7]))) + yA0;
      float eA1 = (((A1[0] + A1[1]) + (A1[2] + A1[3])) + ((A1[4] + A1[5]) + (A1[6] + A1[7]))) + yA1;
      eA0 += __shfl_xor(eA0, 32, 64);
      eA1 += __shfl_xor(eA1, 32, 64);
      if (h == 0) tile32[n * 33 + fl] = pk(eA0, eA1);
      if (hasB) {
        float eB0 = (((B0[0] + B0[1]) + (B0[2] + B0[3])) + ((B0[4] + B0[5]) + (B0[6] + B0[7]))) + yB0;
        float eB1 = (((B1[0] + B1[1]) + (B1[2] + B1[3])) + ((B1[4] + B1[5]) + (B1[6] + B1[7]))) + yB1;
        eB0 += __shfl_xor(eB0, 32, 64);
        eB1 += __shfl_xor(eB1, 32, 64);
        if (h == 0) tile32[nB * 33 + fl] = pk(eB0, eB1);
      }
    }
  } else {
    // fallback (statistically never): indices straight from global csr2
    for (int n = wv; n < rows; n += 4) {
      const int st = sstart[n];
      const int d = sstart[n + 1] - st;
      const int m = (d + 1 - h) >> 1;
      u32 us = xu[(size_t)(base + n) * 32 + fl];
      float e0 = sch * blo(us), e1 = sch * bhi(us);
      for (int i2 = 0; i2 < m; ++i2) {
        u32 u_ = xu[(size_t)csr2[st + h + 2 * i2] * 32 + fl];
        e0 += blo(u_); e1 += bhi(u_);
      }
      e0 += __shfl_xor(e0, 32, 64);
      e1 += __shfl_xor(e1, 32, 64);
      if (h == 0) tile32[n * 33 + fl] = pk(e0, e1);
    }
  }
  __syncthreads();

  // MLP. lane = node row; wave owns cols [jcs, jcs+16), jcs in SGPR.
  // Packed k-loop: one u32 read = 2 k-steps.
  const int jcs = __builtin_amdgcn_readfirstlane(wv * 16);
  const int jh = jcs >> 1;
  float acc[16];
#pragma unroll
  for (int j = 0; j < 16; ++j) acc[j] = b1[jcs + j];
#pragma unroll 4
  for (int kk = 0; kk < 32; ++kk) {
    u32 pr = tile32[lane * 33 + kk];
    float a0 = blo(pr), a1 = bhi(pr);
#pragma unroll
    for (int j = 0; j < 16; ++j)
      acc[j] = fmaf(a1, W1[(2 * kk + 1) * 64 + jcs + j],
                    fmaf(a0, W1[(2 * kk) * 64 + jcs + j], acc[j]));
  }
  __syncthreads();
#pragma unroll
  for (int j2 = 0; j2 < 8; ++j2)
    tile32[lane * 33 + jh + j2] =
        pk(fmaxf(acc[2 * j2], 0.0f), fmaxf(acc[2 * j2 + 1], 0.0f));
  __syncthreads();

#pragma unroll
  for (int j = 0; j < 16; ++j) acc[j] = b2[jcs + j];
#pragma unroll 4
  for (int kk = 0; kk < 32; ++kk) {
    u32 pr = tile32[lane * 33 + kk];
    float a0 = blo(pr), a1 = bhi(pr);
#pragma unroll
    for (int j = 0; j < 16; ++j)
      acc[j] = fmaf(a1, W2[(2 * kk + 1) * 64 + jcs + j],
                    fmaf(a0, W2[(2 * kk) * 64 + jcs + j], acc[j]));
  }
  __syncthreads();
#pragma unroll
  for (int j2 = 0; j2 < 8; ++j2)
    tile32[lane * 33 + jh + j2] =
        pk(fmaxf(acc[2 * j2], 0.0f), fmaxf(acc[2 * j2 + 1], 0.0f));
  __syncthreads();

  // coalesced packed store: 2 rows per iteration across the wave
  u32* o32 = (u32*)outh;
  for (int n2 = wv * 2 + h; n2 < rows; n2 += 8)
    o32[(size_t)(base + n2) * 32 + fl] = tile32[n2 * 33 + fl];
}

// out(f32) = bf16_in @ Wf + bf
__global__ __launch_bounds__(256) void k_final(const u16* __restrict__ in,
                                               const float* __restrict__ Wf,
                                               const float* __restrict__ bf,
                                               float* __restrict__ out) {
  __shared__ float tile[64 * 65];
  const int lane = threadIdx.x & 63;
  const int wv = threadIdx.x >> 6;
  const int base = blockIdx.x * 64;
  const int rows = min(64, NN - base);
  const int jcs = __builtin_amdgcn_readfirstlane(wv * 16);

  for (int n = wv; n < rows; n += 4)
    tile[n * 65 + lane] = b2f(in[(size_t)(base + n) * DIM + lane]);
  __syncthreads();

  float acc[16];
#pragma unroll
  for (int j = 0; j < 16; ++j) acc[j] = bf[jcs + j];
#pragma unroll 4
  for (int k = 0; k < 64; ++k) {
    float a = tile[lane * 65 + k];
#pragma unroll
    for (int j = 0; j < 16; ++j) acc[j] = fmaf(a, Wf[k * 64 + jcs + j], acc[j]);
  }
  __syncthreads();
#pragma unroll
  for (int j = 0; j < 16; ++j) tile[lane * 65 + jcs + j] = acc[j];
  __syncthreads();

  for (int n = wv; n < rows; n += 4)
    out[(size_t)(base + n) * DIM + lane] = tile[n * 65 + lane];
}

extern "C" void kernel_launch(void* const* d_in, const int* in_sizes, int n_in,
                              void* d_out, int out_size, void* d_ws, size_t ws_size,
                              hipStream_t stream) {
  const float* x   = (const float*)d_in[0];
  const int*   ei  = (const int*)d_in[1];
  const float* W1  = (const float*)d_in[2];
  const float* b1  = (const float*)d_in[3];
  const float* W2  = (const float*)d_in[4];
  const float* b2  = (const float*)d_in[5];
  const float* eps = (const float*)d_in[6];
  const float* Wf  = (const float*)d_in[7];
  const float* bf  = (const float*)d_in[8];

  // ws: xh0 | xh1 [NN*64 u16 each, 12.8MB] | csr2[NE, 6.4MB] | nstartP[NN+1]
  //     | Hmat[MH, 626KB] | bsum[NSB2] | rstart[NR+1]   (~33.1 MB)
  u16* xh0 = (u16*)d_ws;
  u16* xh1 = xh0 + (size_t)NN * DIM;
  int* csr2    = (int*)(xh1 + (size_t)NN * DIM);
  int* nstartP = csr2 + NE;
  int* Hmat    = nstartP + NN + 1;
  int* bsum    = Hmat + MH;
  int* rstart  = bsum + NSB2;
  // bb lives in d_out (dead until k_final writes it at the end)
  int* bb = (int*)d_out;

  const int grid_conv = NN * DIM / 4 / 256;  // 6250, exact
  const int grid_mlp  = (NN + 63) / 64;      // 1563

  k_tobf<<<grid_conv, 256, 0, stream>>>(x, xh0);
  k_phist<<<BP, 256, 0, stream>>>(ei, Hmat);
  k_sA<<<NSB2, 256, 0, stream>>>(Hmat, bsum);
  k_sB<<<1, 1024, 0, stream>>>(bsum);
  k_sC<<<NSB2, 256, 0, stream>>>(Hmat, bsum);
  k_rex<<<1, 512, 0, stream>>>(Hmat, rstart, nstartP);
  k_pfill<<<BP, 256, 0, stream>>>(ei, Hmat, bb);
  k_rsort<<<NR, 256, 0, stream>>>(rstart, bb, csr2, nstartP);

  // bf16 ping-pong: L0 xh0->xh1, L1 xh1->xh0, L2 xh0->xh1, final xh1->d_out
  k_gin<<<grid_mlp, 256, 0, stream>>>(xh0, nstartP, csr2, eps, 0,
                                      W1, b1, W2, b2, xh1);
  k_gin<<<grid_mlp, 256, 0, stream>>>(xh1, nstartP, csr2, eps, 1,
                                      W1 + 64 * 64, b1 + 64, W2 + 64 * 64, b2 + 64, xh0);
  k_gin<<<grid_mlp, 256, 0, stream>>>(xh0, nstartP, csr2, eps, 2,
                                      W1 + 2 * 64 * 64, b1 + 2 * 64, W2 + 2 * 64 * 64, b2 + 2 * 64, xh1);
  k_final<<<grid_mlp, 256, 0, stream>>>(xh1, Wf, bf, (float*)d_out);
}